// Round 9
// baseline (757.099 us; speedup 1.0000x reference)
//
#include <hip/hip_runtime.h>
#include <math.h>
#include <stdint.h>

// ---------------------------------------------------------------------------
// IntraModalContrastive loss. Round 15:
//  - GEMM: BK=32 with THREE LDS buffers and 2-deep prefetch. At iter t we
//    stage tile t+2 and vmcnt(8)-wait for tile t (issued 2 iterations ago,
//    ~500-700 cyc elapsed -> L2 latency covered). R14's 1-deep BK=32 waited
//    on loads issued ~200 cyc earlier -> exposed latency, regressed.
//    48 KB LDS -> 3 blocks/CU (12 waves) vs R13's 2.
//  - Swizzle identical to R14 (numerically verified).
//  - row_loss v6 unchanged (256 thr, reg retention, (256,4) bounds).
// ---------------------------------------------------------------------------

typedef __attribute__((ext_vector_type(4))) float  floatx4;
typedef __attribute__((ext_vector_type(8))) __bf16 bf16x8;

__device__ __forceinline__ unsigned short f2bf(float f)
{
    unsigned u = __float_as_uint(f);
    unsigned r = (u + 0x7FFFu + ((u >> 16) & 1u)) >> 16;
    return (unsigned short)r;
}

__device__ __forceinline__ float bf2f(unsigned short u)
{
    return __uint_as_float((unsigned)u << 16);
}

__device__ __forceinline__ void gld_lds16(const void* g, void* l)
{
    __builtin_amdgcn_global_load_lds(
        (const __attribute__((address_space(1))) void*)g,
        (__attribute__((address_space(3))) void*)(uint32_t)(uintptr_t)l,
        16, 0, 0);
}

#define EPW 136   // epilogue LDS row stride in shorts (272 B, 16B-aligned)

// Stage one 128x32 bf16 tile (8 KB) global -> LDS, source-side swizzled:
// LDS [row][slot s] holds global chunk s ^ ((row>>1)&3)  (chunks of 8 bf16).
// Dest is linear (wave-uniform base + lane*16) as global_load_lds requires.
// 2 vmem ops per thread.
__device__ __forceinline__ void stage_tile32(
    const unsigned short* __restrict__ g, int ld, int k0,
    unsigned short* lds, int t)
{
    const int c = (t & 3) ^ ((t >> 3) & 3);   // == (t&3) ^ ((row>>1)&3)
#pragma unroll
    for (int it = 0; it < 2; ++it) {
        const int row = it * 64 + (t >> 2);
        gld_lds16(g + (size_t)row * ld + k0 + c * 8,
                  lds + (it * 256 + t) * 8);
    }
}

// ---------- bf16 MFMA GEMM: 128x128 tile, 256 thr, BK=32, 3-buf 2-deep -----
// C[M,N] = ep(scale*(A @ B^T) + bias); A: MxK bf16 (lda), B: NxK bf16 (ldb).
// grid.x == (M/128)*(N/128), divisible by 8; M/128 divisible by 4;
// K divisible by 32, K >= 96.
__global__ __launch_bounds__(256) void gemm_bt_mfma(
    const unsigned short* __restrict__ A, int lda,
    const unsigned short* __restrict__ B, int ldb,
    unsigned short* __restrict__ C, int ldc, int M, int N, int K,
    const float* __restrict__ bias, int relu, float scale)
{
    // buf b at smem + b*8192 shorts (As 4096 + Bs 4096 = 16 KB each),
    // 3 bufs = 49152 B -> 3 blocks/CU. Epilogue reuses [0, 128*EPW).
    __shared__ __align__(16) unsigned short smem[24576];

    const int num_n = N >> 7;
    const int per   = gridDim.x >> 3;
    const int pid   = blockIdx.x;
    const int npid  = (pid & 7) * per + (pid >> 3);   // XCD-contiguous
    const int width = 4 * num_n;
    const int group = npid / width;
    const int rem   = npid - group * width;
    const int pm    = group * 4 + (rem & 3);
    const int pn    = rem >> 2;

    const int t    = threadIdx.x;
    const int lane = t & 63;
    const int w    = t >> 6;        // 0..3
    const int wr   = w >> 1;        // 0..1 (64-row band)
    const int wc   = w & 1;         // 0..1 (64-col band)
    const size_t m0 = (size_t)pm * 128;
    const size_t n0 = (size_t)pn * 128;

    floatx4 acc[4][4] = {};

    const unsigned short* Abase = A + m0 * (size_t)lda;
    const unsigned short* Bbase = B + n0 * (size_t)ldb;

    // Loop-invariant swizzled fragment offsets (shorts, rel. to buf base).
    // Fragment (row r, k-chunk cc = lane>>4) lives at r*32 + (cc^((r>>1)&3))*8.
    int aoff[4], boff[4];
    const int cc = lane >> 4;
#pragma unroll
    for (int i = 0; i < 4; ++i) {
        const int ra = wr * 64 + i * 16 + (lane & 15);
        const int rb = wc * 64 + i * 16 + (lane & 15);
        aoff[i] = ra * 32 + ((cc ^ ((ra >> 1) & 3)) << 3);
        boff[i] = rb * 32 + ((cc ^ ((rb >> 1) & 3)) << 3);
    }

    const int NT = K >> 5;

    // prologue: stage tiles 0 and 1 (8 vmem ops outstanding).
    stage_tile32(Abase, lda, 0, smem, t);
    stage_tile32(Bbase, ldb, 0, smem + 4096, t);
    stage_tile32(Abase, lda, 32, smem + 8192, t);
    stage_tile32(Bbase, ldb, 32, smem + 8192 + 4096, t);

    int cur = 0;           // buf index of tile t  (t % 3) * 8192
    int nxt2 = 16384;      // buf index of tile t+2
    for (int kt = 0; kt < NT; ++kt) {
        // Stage tile kt+2 into buf[(kt+2)%3] (the buffer tile kt-1 used;
        // its reads drained at iter kt-1's lgkmcnt+barrier). Then wait for
        // tile kt only: its 4 loads are the oldest of the <=12 outstanding.
        if (kt + 2 < NT) {
            unsigned short* nb = smem + nxt2;
            stage_tile32(Abase, lda, (kt + 2) << 5, nb, t);
            stage_tile32(Bbase, ldb, (kt + 2) << 5, nb + 4096, t);
            asm volatile("s_waitcnt vmcnt(8)" ::: "memory");
        } else if (kt + 1 < NT) {
            asm volatile("s_waitcnt vmcnt(4)" ::: "memory");
        } else {
            asm volatile("s_waitcnt vmcnt(0)" ::: "memory");
        }
        __builtin_amdgcn_sched_barrier(0);
        __builtin_amdgcn_s_barrier();      // tile kt visible to all waves
        __builtin_amdgcn_sched_barrier(0);

        const unsigned short* As = smem + cur;
        const unsigned short* Bs = As + 4096;

        bf16x8 af[4], bfr[4];
#pragma unroll
        for (int i = 0; i < 4; ++i) {
            af[i]  = *(const bf16x8*)(As + aoff[i]);
            bfr[i] = *(const bf16x8*)(Bs + boff[i]);
        }
#pragma unroll
        for (int i = 0; i < 4; ++i)
#pragma unroll
            for (int j = 0; j < 4; ++j)
                acc[i][j] = __builtin_amdgcn_mfma_f32_16x16x32_bf16(
                    af[i], bfr[j], acc[i][j], 0, 0, 0);

        // all ds_reads of buf[kt%3] complete in every thread before any
        // thread may overwrite it (stage of tile kt+3 at iter kt+1).
        asm volatile("s_waitcnt lgkmcnt(0)" ::: "memory");
        __builtin_amdgcn_sched_barrier(0);
        __builtin_amdgcn_s_barrier();
        __builtin_amdgcn_sched_barrier(0);

        cur  += 8192; if (cur  == 24576) cur  = 0;
        nxt2 += 8192; if (nxt2 == 24576) nxt2 = 0;
    }

    // --- epilogue: one 128-row pass through LDS, coalesced uint4 stores ---
    const int col   = lane & 15;
    const int rquad = (lane >> 4) * 4;
#pragma unroll
    for (int j = 0; j < 4; ++j) {
        const int lc = wc * 64 + j * 16 + col;
        const float bv = bias ? bias[n0 + lc] : 0.0f;
#pragma unroll
        for (int i = 0; i < 4; ++i) {
            const int lr0 = wr * 64 + i * 16 + rquad;
#pragma unroll
            for (int r = 0; r < 4; ++r) {
                float v = acc[i][j][r] * scale + bv;
                if (relu) v = fmaxf(v, 0.0f);
                smem[(lr0 + r) * EPW + lc] = f2bf(v);
            }
        }
    }
    __syncthreads();
#pragma unroll
    for (int h = 0; h < 2; ++h) {
        const int cr = h * 64 + (t >> 2);   // 0..127
        const int cq = t & 3;
#pragma unroll
        for (int q = 0; q < 4; ++q) {
            const int chunk = cq + q * 4;           // 0..15
            uint4 v = *(const uint4*)(smem + cr * EPW + chunk * 8);
            *(uint4*)(C + (m0 + cr) * (size_t)ldc + n0 + chunk * 8) = v;
        }
    }
}

// ---------- elementwise fp32 -> bf16 cast -----------------------------------
__global__ __launch_bounds__(256) void cast_bf16_kernel(
    const float* __restrict__ in, unsigned short* __restrict__ out, int n4)
{
    const int i = blockIdx.x * 256 + threadIdx.x;
    if (i < n4) {
        float4 v = *(const float4*)(in + (size_t)i * 4);
        ushort4 o;
        o.x = f2bf(v.x); o.y = f2bf(v.y); o.z = f2bf(v.z); o.w = f2bf(v.w);
        *(ushort4*)(out + (size_t)i * 4) = o;
    }
}

// ---------- transpose + cast: W[K,N] fp32 -> WT[N,K] bf16 -------------------
__global__ __launch_bounds__(256) void transpose_cast_kernel(
    const float* __restrict__ W, unsigned short* __restrict__ WT, int K, int N)
{
    __shared__ float tile[32][33];
    const int k0 = blockIdx.y * 32;
    const int n0 = blockIdx.x * 32;
    const int tr = threadIdx.x >> 3;
    const int tc = (threadIdx.x & 7) * 4;

    float4 v = *(const float4*)(W + (size_t)(k0 + tr) * N + n0 + tc);
    tile[tr][tc + 0] = v.x;
    tile[tr][tc + 1] = v.y;
    tile[tr][tc + 2] = v.z;
    tile[tr][tc + 3] = v.w;
    __syncthreads();

    ushort4 o;
    o.x = f2bf(tile[tc + 0][tr]);
    o.y = f2bf(tile[tc + 1][tr]);
    o.z = f2bf(tile[tc + 2][tr]);
    o.w = f2bf(tile[tc + 3][tr]);
    *(ushort4*)(WT + (size_t)(n0 + tr) * K + k0 + tc) = o;
}

// ---------- row L2-normalize, bf16 in-place, width 512 ----------------------
__global__ __launch_bounds__(128) void normalize_bf16_kernel(
    unsigned short* __restrict__ X)
{
    const int r = blockIdx.x;
    const int t = threadIdx.x;
    unsigned short* row = X + (size_t)r * 512;
    ushort4 u = *(const ushort4*)(row + t * 4);
    float x0 = bf2f(u.x), x1 = bf2f(u.y), x2 = bf2f(u.z), x3 = bf2f(u.w);
    float ss = x0 * x0 + x1 * x1 + x2 * x2 + x3 * x3;
#pragma unroll
    for (int off = 32; off > 0; off >>= 1) ss += __shfl_down(ss, off, 64);
    __shared__ float sred[2];
    if ((t & 63) == 0) sred[t >> 6] = ss;
    __syncthreads();
    float inv = 1.0f / sqrtf(sred[0] + sred[1]);
    ushort4 o;
    o.x = f2bf(x0 * inv); o.y = f2bf(x1 * inv);
    o.z = f2bf(x2 * inv); o.w = f2bf(x3 * inv);
    *(ushort4*)(row + t * 4) = o;
}

// ---------- per-row mining + loss (v6: 256 thr, raw-reg retention) ----------
// accum is a 2x64 float array; each block adds into slot [midx*64 + blk&63].
__global__ __launch_bounds__(256, 4) void row_loss_kernel(
    const unsigned short* __restrict__ S, int row_base,
    const float* __restrict__ mw, int midx, float* __restrict__ accum)
{
    __shared__ unsigned hist[4096];         // 16 KB
    __shared__ unsigned wtot[4];
    __shared__ float fred[4];
    __shared__ unsigned sh_b;
    __shared__ float sh_diag;

    const int t    = threadIdx.x;           // 0..255
    const int lane = t & 63;
    const int wv   = t >> 6;                // 0..3
    const int i    = row_base + blockIdx.x; // diag column index
    const unsigned short* Srow = S + (size_t)blockIdx.x * 8192;

    for (int b = t; b < 4096; b += 256) hist[b] = 0;

    // single global read: 32 elements as raw bf16 in 8 VGPRs.
    // segment seg (0..3) covers columns seg*2048 + t*8 .. +7.
    uint4 raw[4];
#pragma unroll
    for (int seg = 0; seg < 4; ++seg)
        raw[seg] = *(const uint4*)(Srow + seg * 2048 + t * 8);
    __syncthreads();     // hist zeroed

#pragma unroll
    for (int seg = 0; seg < 4; ++seg) {
        const unsigned short* e = (const unsigned short*)&raw[seg];
#pragma unroll
        for (int q = 0; q < 8; ++q) {
            const int j = seg * 2048 + t * 8 + q;
            const float s = bf2f(e[q]);
            if (j != i && s <= 9.0f) {
                int k = (int)((s + 10.25f) * 200.0f);
                k = k < 1 ? 1 : (k > 4095 ? 4095 : k);
                atomicAdd(&hist[k], 1u);
            }
        }
    }
    __syncthreads();

    // suffix-sum over 4096 bins; thread t owns bins [t*16, t*16+16)
    unsigned local = 0;
#pragma unroll
    for (int q = 0; q < 16; ++q) local += hist[t * 16 + q];
    unsigned suf = local;
#pragma unroll
    for (int off = 1; off < 64; off <<= 1) {
        unsigned v = __shfl_down(suf, off, 64);
        if (lane + off < 64) suf += v;
    }
    if (lane == 0) wtot[wv] = suf;
    __syncthreads();
    unsigned wsuf = 0;
#pragma unroll
    for (int q = 0; q < 4; ++q) wsuf += (q > wv) ? wtot[q] : 0u;
    suf += wsuf;

    const unsigned target = 4096;
    const unsigned above  = suf - local;
    if (suf >= target && above < target) {
        unsigned cum = above;
        int bsel = t * 16;
#pragma unroll
        for (int q = 15; q >= 0; --q) {
            unsigned c = hist[t * 16 + q];
            if (cum + c >= target) { bsel = t * 16 + q; break; }
            cum += c;
        }
        sh_b = (unsigned)bsel;
    }
    if (t == 0 && suf < target) sh_b = 1u;
    __syncthreads();
    const unsigned bsel = sh_b;

    float lsum = 0.0f;
#pragma unroll
    for (int seg = 0; seg < 4; ++seg) {
        const unsigned short* e = (const unsigned short*)&raw[seg];
#pragma unroll
        for (int q = 0; q < 8; ++q) {
            const int j = seg * 2048 + t * 8 + q;
            const float s = bf2f(e[q]);
            bool diag  = (j == i);
            bool noise = (!diag && s > 9.0f);
            int k = (int)((s + 10.25f) * 200.0f);
            k = k < 1 ? 1 : (k > 4095 ? 4095 : k);
            bool hard = !diag && !noise && ((unsigned)k >= bsel);
            float wgt = noise ? 0.5f : (hard ? 1.5f : 1.0f);
            float ws = s * wgt;
            if (diag) sh_diag = ws;
            lsum += __expf(ws - 16.0f);
        }
    }
#pragma unroll
    for (int off = 32; off > 0; off >>= 1)
        lsum += __shfl_down(lsum, off, 64);
    if (lane == 0) fred[wv] = lsum;
    __syncthreads();
    if (t == 0) {
        float total = fred[0] + fred[1] + fred[2] + fred[3];
        float lse = 16.0f + logf(total);
        float ce = lse - sh_diag;
        atomicAdd(&accum[midx * 64 + (blockIdx.x & 63)],
                  ce * mw[(size_t)i * 2 + midx]);
    }
}

__global__ void zero_kernel(float* __restrict__ accum)
{
    if (threadIdx.x < 128) accum[threadIdx.x] = 0.0f;
}

__global__ void finalize_kernel(const float* __restrict__ accum,
                                float* __restrict__ out)
{
    float s = 0.0f;
    for (int q = 0; q < 128; ++q) s += accum[q];
    out[0] = s * (1.0f / 16384.0f);
}

// ---------------------------------------------------------------------------
extern "C" void kernel_launch(void* const* d_in, const int* in_sizes, int n_in,
                              void* d_out, int out_size, void* d_ws, size_t ws_size,
                              hipStream_t stream)
{
    (void)in_sizes; (void)n_in; (void)out_size; (void)ws_size;

    const float* id_emb = (const float*)d_in[0];
    const float* feats[2] = { (const float*)d_in[1], (const float*)d_in[2] };
    const float* mw     = (const float*)d_in[3];
    const float* Wa[2]  = { (const float*)d_in[4],  (const float*)d_in[6]  };
    const float* ba[2]  = { (const float*)d_in[5],  (const float*)d_in[7]  };
    const float* W1[2]  = { (const float*)d_in[8],  (const float*)d_in[12] };
    const float* b1[2]  = { (const float*)d_in[9],  (const float*)d_in[13] };
    const float* W2[2]  = { (const float*)d_in[10], (const float*)d_in[14] };
    const float* b2[2]  = { (const float*)d_in[11], (const float*)d_in[15] };
    const int    Fdim[2] = { 768, 2048 };

    // Layout: X is NOT aliased (id half persists across modalities);
    // S (64 MB) aliases featb+H (both dead during the sim phase).
    char* p = (char*)d_ws;
    unsigned short* WaT   = (unsigned short*)p; p += (size_t)1024 * 2048 * 2;  //  4 MB
    unsigned short* W1T   = (unsigned short*)p; p += (size_t)1024 * 1024 * 2;  //  2 MB
    unsigned short* W2T   = (unsigned short*)p; p += (size_t)512  * 1024 * 2;  //  1 MB
    unsigned short* X     = (unsigned short*)p; p += (size_t)16384 * 1024 * 2; // 32 MB
    unsigned short* featb = (unsigned short*)p; p += (size_t)8192 * 2048 * 2;  // 32 MB
    unsigned short* H     = (unsigned short*)p; p += (size_t)16384 * 1024 * 2; // 32 MB
    unsigned short* PB    = (unsigned short*)p; p += (size_t)16384 * 512  * 2; // 16 MB
    float*          accum = (float*)p;          // 128 floats (2 x 64 slots)
    unsigned short* S     = featb;               // 4096x8192 bf16 = 64 MB

    zero_kernel<<<1, 128, 0, stream>>>(accum);

    // id embeddings -> bf16 lower half of X, once (X never aliased)
    cast_bf16_kernel<<<(8192 * 1024 / 4 + 255) / 256, 256, 0, stream>>>(
        id_emb, X + (size_t)8192 * 1024, 8192 * 1024 / 4);

    for (int m = 0; m < 2; ++m) {
        const int F = Fdim[m];

        cast_bf16_kernel<<<(8192 * F / 4 + 255) / 256, 256, 0, stream>>>(
            feats[m], featb, 8192 * F / 4);
        transpose_cast_kernel<<<dim3(1024 / 32, F / 32), 256, 0, stream>>>(
            Wa[m], WaT, F, 1024);
        transpose_cast_kernel<<<dim3(1024 / 32, 1024 / 32), 256, 0, stream>>>(
            W1[m], W1T, 1024, 1024);
        transpose_cast_kernel<<<dim3(512 / 32, 1024 / 32), 256, 0, stream>>>(
            W2[m], W2T, 1024, 512);

        // X[0:8192] = feat @ Wa + ba   (8192 x 1024, bf16)
        gemm_bt_mfma<<<(8192 / 128) * (1024 / 128), 256, 0, stream>>>(
            featb, F, WaT, F, X, 1024, 8192, 1024, F, ba[m], 0, 1.0f);

        // H = relu(X @ W1 + b1)        (16384 x 1024, bf16)
        gemm_bt_mfma<<<(16384 / 128) * (1024 / 128), 256, 0, stream>>>(
            X, 1024, W1T, 1024, H, 1024, 16384, 1024, 1024, b1[m], 1, 1.0f);
        // PB = H @ W2 + b2             (16384 x 512, bf16)
        gemm_bt_mfma<<<(16384 / 128) * (512 / 128), 256, 0, stream>>>(
            H, 1024, W2T, 1024, PB, 512, 16384, 512, 1024, b2[m], 0, 1.0f);
        // normalize in place           (modal rows 0:8192, id rows 8192:)
        normalize_bf16_kernel<<<16384, 128, 0, stream>>>(PB);

        const unsigned short* mproj = PB;
        const unsigned short* iproj = PB + (size_t)8192 * 512;

        for (int c = 0; c < 2; ++c) {
            // S = 10 * id_proj[chunk 4096] @ modal_proj^T  (4096 x 8192 bf16)
            gemm_bt_mfma<<<(4096 / 128) * (8192 / 128), 256, 0, stream>>>(
                iproj + (size_t)c * 4096 * 512, 512, mproj, 512,
                S, 8192, 4096, 8192, 512, nullptr, 0, 10.0f);
            row_loss_kernel<<<4096, 256, 0, stream>>>(
                S, c * 4096, mw, m, accum);
        }
    }

    finalize_kernel<<<1, 1, 0, stream>>>(accum, (float*)d_out);
}

// Round 10
// 688.481 us; speedup vs baseline: 1.0997x; 1.0997x over previous
//
#include <hip/hip_runtime.h>
#include <math.h>
#include <stdint.h>

// ---------------------------------------------------------------------------
// IntraModalContrastive loss. Round 16:
//  - NEW gemm_bt_256: 256x256 tile, 512 thr (8 waves 2x4), BK=64, 128 KB LDS
//    double-buffer, phase-interleaved K-loop (2 phases/K-tile: ks=0/ks=1).
//    Per wave output 128x64 -> 375 B LDS-read per MFMA (vs 512 at 128 tile,
//    which R13-R15 showed is LDS-BW-saturated at ~700 TF). Counted vmcnt(4)
//    once per K-tile; stage->read race ruled out by barrier ordering (stage
//    targets the dbuf whose reads finished one tile ago). setprio around
//    MFMA clusters (T5 pays in phase-split schedules).
//    Used for H (16384x1024) and S (4096x8192) GEMMs.
//  - Adapter + PB keep the R13 128x128 kernel (grids of 128 blocks would
//    idle half the chip at 256 tiles).
//  - row_loss v6 unchanged.
// ---------------------------------------------------------------------------

typedef __attribute__((ext_vector_type(4))) float  floatx4;
typedef __attribute__((ext_vector_type(8))) __bf16 bf16x8;

__device__ __forceinline__ unsigned short f2bf(float f)
{
    unsigned u = __float_as_uint(f);
    unsigned r = (u + 0x7FFFu + ((u >> 16) & 1u)) >> 16;
    return (unsigned short)r;
}

__device__ __forceinline__ float bf2f(unsigned short u)
{
    return __uint_as_float((unsigned)u << 16);
}

__device__ __forceinline__ void gld_lds16(const void* g, void* l)
{
    __builtin_amdgcn_global_load_lds(
        (const __attribute__((address_space(1))) void*)g,
        (__attribute__((address_space(3))) void*)(uint32_t)(uintptr_t)l,
        16, 0, 0);
}

#define EPW  136  // 128-wide epilogue LDS row stride in shorts
#define EPW2 264  // 256-wide epilogue LDS row stride in shorts

// ===========================================================================
// 256x256 kernel pieces
// ===========================================================================

// Stage one 128x64 bf16 half-tile (16 KB), 512 threads, 2 loads each.
// LDS position li*16B holds global (row=li>>3, chunk=(li&7)^(row&7)).
__device__ __forceinline__ void stage_half256(
    const unsigned short* __restrict__ g, int ld, int k0,
    unsigned short* lds, int t)
{
#pragma unroll
    for (int it = 0; it < 2; ++it) {
        const int li  = it * 512 + t;        // 0..1023
        const int row = li >> 3;             // 0..127
        const int c   = (li & 7) ^ (row & 7);
        gld_lds16(g + (size_t)row * ld + k0 + c * 8, lds + li * 8);
    }
}

// C[M,N] = ep(scale*(A @ B^T) + bias). Requires M%256==0, M/256%4==0? no:
// grid.x == (M/256)*(N/256) divisible by 8; M/256 divisible by 4; K%64==0.
__global__ __launch_bounds__(512, 2) void gemm_bt_256(
    const unsigned short* __restrict__ A, int lda,
    const unsigned short* __restrict__ B, int ldb,
    unsigned short* __restrict__ C, int ldc, int M, int N, int K,
    const float* __restrict__ bias, int relu, float scale)
{
    // dbuf d (d=0,1) at d*32768 shorts: A half h at +h*8192, B half h at
    // +16384+h*8192. Total 131072 B. Epilogue reuses [0, 128*EPW2).
    __shared__ __align__(16) unsigned short smem[65536];

    const int num_n = N >> 8;
    const int per   = gridDim.x >> 3;
    const int pid   = blockIdx.x;
    const int npid  = (pid & 7) * per + (pid >> 3);   // XCD-contiguous
    const int width = 4 * num_n;
    const int group = npid / width;
    const int rem   = npid - group * width;
    const int pm    = group * 4 + (rem & 3);
    const int pn    = rem >> 2;

    const int t    = threadIdx.x;
    const int lane = t & 63;
    const int w    = t >> 6;        // 0..7
    const int wr   = w >> 2;        // 0..1 (128-row band)
    const int wc   = w & 3;         // 0..3 (64-col band)
    const size_t m0 = (size_t)pm * 256;
    const size_t n0 = (size_t)pn * 256;

    floatx4 acc[8][4] = {};

    const unsigned short* Abase = A + m0 * (size_t)lda;
    const unsigned short* Bbase = B + n0 * (size_t)ldb;

    // Fragment offsets (shorts, relative to dbuf base).
    // A frag (i,ks): half=wr, row-in-half rr=i*16+(lane&15).
    // B frag (j,ks): rb=wc*64+j*16+(lane&15); half=rb>>7, rr=rb&127.
    int aoff[8][2], boff[4][2];
#pragma unroll
    for (int ks = 0; ks < 2; ++ks) {
        const int cc = ks * 4 + (lane >> 4);
#pragma unroll
        for (int i = 0; i < 8; ++i) {
            const int rr = i * 16 + (lane & 15);
            aoff[i][ks] = wr * 8192 + rr * 64 + ((cc ^ (rr & 7)) << 3);
        }
#pragma unroll
        for (int j = 0; j < 4; ++j) {
            const int rb = wc * 64 + j * 16 + (lane & 15);
            const int rr = rb & 127;
            boff[j][ks] = 16384 + (rb >> 7) * 8192 + rr * 64
                        + ((cc ^ (rr & 7)) << 3);
        }
    }

    const int NT = K >> 6;

    // prologue: stage tile 0 into dbuf0 (8 vmem/thread outstanding)
    stage_half256(Abase, lda, 0, smem, t);
    stage_half256(Abase + (size_t)128 * lda, lda, 0, smem + 8192, t);
    stage_half256(Bbase, ldb, 0, smem + 16384, t);
    stage_half256(Bbase + (size_t)128 * ldb, ldb, 0, smem + 24576, t);

    for (int kt = 0; kt < NT; ++kt) {
        unsigned short* cb = smem + (kt & 1) * 32768;
        unsigned short* nb = smem + ((kt + 1) & 1) * 32768;
        const int kn = (kt + 1) << 6;

        // ---- phase 0 (ks=0): stage A halves of kt+1; wait for tile kt ----
        // nb holds tile kt-1, fully read (its last ds_reads completed before
        // the end-barrier of tile kt-1 phase 1, which all waves crossed).
        if (kt + 1 < NT) {
            stage_half256(Abase, lda, kn, nb, t);
            stage_half256(Abase + (size_t)128 * lda, lda, kn, nb + 8192, t);
            // outstanding: 8 (tile kt, issued one tile ago) + 4 new = 12;
            // retire the oldest 8 -> tile kt fully in LDS.
            asm volatile("s_waitcnt vmcnt(4)" ::: "memory");
        } else {
            asm volatile("s_waitcnt vmcnt(0)" ::: "memory");
        }
        __builtin_amdgcn_sched_barrier(0);
        __builtin_amdgcn_s_barrier();      // tile kt visible to all waves
        __builtin_amdgcn_sched_barrier(0);

        {
            bf16x8 af[8], bf[4];
#pragma unroll
            for (int i = 0; i < 8; ++i) af[i] = *(const bf16x8*)(cb + aoff[i][0]);
#pragma unroll
            for (int j = 0; j < 4; ++j) bf[j] = *(const bf16x8*)(cb + boff[j][0]);
            __builtin_amdgcn_s_setprio(1);
#pragma unroll
            for (int i = 0; i < 8; ++i)
#pragma unroll
                for (int j = 0; j < 4; ++j)
                    acc[i][j] = __builtin_amdgcn_mfma_f32_16x16x32_bf16(
                        af[i], bf[j], acc[i][j], 0, 0, 0);
            __builtin_amdgcn_s_setprio(0);
        }
        __builtin_amdgcn_sched_barrier(0);
        __builtin_amdgcn_s_barrier();
        __builtin_amdgcn_sched_barrier(0);

        // ---- phase 1 (ks=1): stage B halves of kt+1 ----
        if (kt + 1 < NT) {
            stage_half256(Bbase, ldb, kn, nb + 16384, t);
            stage_half256(Bbase + (size_t)128 * ldb, ldb, kn, nb + 24576, t);
        }
        {
            bf16x8 af[8], bf[4];
#pragma unroll
            for (int i = 0; i < 8; ++i) af[i] = *(const bf16x8*)(cb + aoff[i][1]);
#pragma unroll
            for (int j = 0; j < 4; ++j) bf[j] = *(const bf16x8*)(cb + boff[j][1]);
            __builtin_amdgcn_s_setprio(1);
#pragma unroll
            for (int i = 0; i < 8; ++i)
#pragma unroll
                for (int j = 0; j < 4; ++j)
                    acc[i][j] = __builtin_amdgcn_mfma_f32_16x16x32_bf16(
                        af[i], bf[j], acc[i][j], 0, 0, 0);
            __builtin_amdgcn_s_setprio(0);
        }
        __builtin_amdgcn_sched_barrier(0);
        __builtin_amdgcn_s_barrier();
        __builtin_amdgcn_sched_barrier(0);
    }

    // --- epilogue: two 128-row passes through LDS, coalesced uint4 stores ---
    const int col   = lane & 15;
    const int rquad = (lane >> 4) * 4;
#pragma unroll
    for (int h = 0; h < 2; ++h) {
        if (wr == h) {
#pragma unroll
            for (int j = 0; j < 4; ++j) {
                const int lc = wc * 64 + j * 16 + col;
                const float bv = bias ? bias[n0 + lc] : 0.0f;
#pragma unroll
                for (int i = 0; i < 8; ++i) {
                    const int lr0 = i * 16 + rquad;
#pragma unroll
                    for (int r = 0; r < 4; ++r) {
                        float v = acc[i][j][r] * scale + bv;
                        if (relu) v = fmaxf(v, 0.0f);
                        smem[(lr0 + r) * EPW2 + lc] = f2bf(v);
                    }
                }
            }
        }
        __syncthreads();
        const int cr = t >> 2;          // 0..127
        const int cq = t & 3;
#pragma unroll
        for (int q = 0; q < 8; ++q) {
            const int chunk = cq + q * 4;           // 0..31
            uint4 v = *(const uint4*)(smem + cr * EPW2 + chunk * 8);
            *(uint4*)(C + (m0 + h * 128 + cr) * (size_t)ldc + n0 + chunk * 8) = v;
        }
        __syncthreads();
    }
}

// ===========================================================================
// 128x128 kernel (R13, verified): adapter + PB GEMMs
// ===========================================================================

__device__ __forceinline__ void stage_tile(
    const unsigned short* __restrict__ g, int ld, int k0,
    unsigned short* lds, int t)
{
#pragma unroll
    for (int it = 0; it < 4; ++it) {
        const int row = it * 32 + (t >> 3);
        const int c   = (t & 7) ^ ((t >> 3) & 7);
        gld_lds16(g + (size_t)row * ld + k0 + c * 8,
                  lds + (it * 256 + t) * 8);
    }
}

__global__ __launch_bounds__(256) void gemm_bt_mfma(
    const unsigned short* __restrict__ A, int lda,
    const unsigned short* __restrict__ B, int ldb,
    unsigned short* __restrict__ C, int ldc, int M, int N, int K,
    const float* __restrict__ bias, int relu, float scale)
{
    __shared__ __align__(16) unsigned short smem[32768];

    const int num_n = N >> 7;
    const int per   = gridDim.x >> 3;
    const int pid   = blockIdx.x;
    const int npid  = (pid & 7) * per + (pid >> 3);
    const int width = 4 * num_n;
    const int group = npid / width;
    const int rem   = npid - group * width;
    const int pm    = group * 4 + (rem & 3);
    const int pn    = rem >> 2;

    const int t    = threadIdx.x;
    const int lane = t & 63;
    const int w    = t >> 6;
    const int wr   = w >> 1;
    const int wc   = w & 1;
    const size_t m0 = (size_t)pm * 128;
    const size_t n0 = (size_t)pn * 128;

    floatx4 acc[4][4] = {};

    const unsigned short* Abase = A + m0 * (size_t)lda;
    const unsigned short* Bbase = B + n0 * (size_t)ldb;

    int aoff[4][2], boff[4][2];
#pragma unroll
    for (int i = 0; i < 4; ++i) {
        const int ra = wr * 64 + i * 16 + (lane & 15);
        const int rb = wc * 64 + i * 16 + (lane & 15);
#pragma unroll
        for (int ks = 0; ks < 2; ++ks) {
            const int cc = ks * 4 + (lane >> 4);
            aoff[i][ks] = ra * 64 + ((cc ^ (ra & 7)) << 3);
            boff[i][ks] = rb * 64 + ((cc ^ (rb & 7)) << 3);
        }
    }

    const int NT = K >> 6;

    stage_tile(Abase, lda, 0, smem, t);
    stage_tile(Bbase, ldb, 0, smem + 8192, t);

    int cur = 0;
    for (int kt = 0; kt < NT; ++kt) {
        if (kt + 1 < NT) {
            unsigned short* nb = smem + (cur ^ 1) * 16384;
            stage_tile(Abase, lda, (kt + 1) << 6, nb, t);
            stage_tile(Bbase, ldb, (kt + 1) << 6, nb + 8192, t);
            asm volatile("s_waitcnt vmcnt(8)" ::: "memory");
        } else {
            asm volatile("s_waitcnt vmcnt(0)" ::: "memory");
        }
        __builtin_amdgcn_sched_barrier(0);
        __builtin_amdgcn_s_barrier();
        __builtin_amdgcn_sched_barrier(0);

        const unsigned short* As = smem + cur * 16384;
        const unsigned short* Bs = As + 8192;

        bf16x8 af[4][2], bfr[4][2];
#pragma unroll
        for (int i = 0; i < 4; ++i) {
#pragma unroll
            for (int ks = 0; ks < 2; ++ks) {
                af[i][ks]  = *(const bf16x8*)(As + aoff[i][ks]);
                bfr[i][ks] = *(const bf16x8*)(Bs + boff[i][ks]);
            }
        }
#pragma unroll
        for (int i = 0; i < 4; ++i)
#pragma unroll
            for (int j = 0; j < 4; ++j)
#pragma unroll
                for (int ks = 0; ks < 2; ++ks)
                    acc[i][j] = __builtin_amdgcn_mfma_f32_16x16x32_bf16(
                        af[i][ks], bfr[j][ks], acc[i][j], 0, 0, 0);

        asm volatile("s_waitcnt lgkmcnt(0)" ::: "memory");
        __builtin_amdgcn_sched_barrier(0);
        __builtin_amdgcn_s_barrier();
        __builtin_amdgcn_sched_barrier(0);
        cur ^= 1;
    }

    const int col   = lane & 15;
    const int rquad = (lane >> 4) * 4;
#pragma unroll
    for (int j = 0; j < 4; ++j) {
        const int lc = wc * 64 + j * 16 + col;
        const float bv = bias ? bias[n0 + lc] : 0.0f;
#pragma unroll
        for (int i = 0; i < 4; ++i) {
            const int lr0 = wr * 64 + i * 16 + rquad;
#pragma unroll
            for (int r = 0; r < 4; ++r) {
                float v = acc[i][j][r] * scale + bv;
                if (relu) v = fmaxf(v, 0.0f);
                smem[(lr0 + r) * EPW + lc] = f2bf(v);
            }
        }
    }
    __syncthreads();
#pragma unroll
    for (int h = 0; h < 2; ++h) {
        const int cr = h * 64 + (t >> 2);
        const int cq = t & 3;
#pragma unroll
        for (int q = 0; q < 4; ++q) {
            const int chunk = cq + q * 4;
            uint4 v = *(const uint4*)(smem + cr * EPW + chunk * 8);
            *(uint4*)(C + (m0 + cr) * (size_t)ldc + n0 + chunk * 8) = v;
        }
    }
}

// ---------- elementwise fp32 -> bf16 cast -----------------------------------
__global__ __launch_bounds__(256) void cast_bf16_kernel(
    const float* __restrict__ in, unsigned short* __restrict__ out, int n4)
{
    const int i = blockIdx.x * 256 + threadIdx.x;
    if (i < n4) {
        float4 v = *(const float4*)(in + (size_t)i * 4);
        ushort4 o;
        o.x = f2bf(v.x); o.y = f2bf(v.y); o.z = f2bf(v.z); o.w = f2bf(v.w);
        *(ushort4*)(out + (size_t)i * 4) = o;
    }
}

// ---------- transpose + cast: W[K,N] fp32 -> WT[N,K] bf16 -------------------
__global__ __launch_bounds__(256) void transpose_cast_kernel(
    const float* __restrict__ W, unsigned short* __restrict__ WT, int K, int N)
{
    __shared__ float tile[32][33];
    const int k0 = blockIdx.y * 32;
    const int n0 = blockIdx.x * 32;
    const int tr = threadIdx.x >> 3;
    const int tc = (threadIdx.x & 7) * 4;

    float4 v = *(const float4*)(W + (size_t)(k0 + tr) * N + n0 + tc);
    tile[tr][tc + 0] = v.x;
    tile[tr][tc + 1] = v.y;
    tile[tr][tc + 2] = v.z;
    tile[tr][tc + 3] = v.w;
    __syncthreads();

    ushort4 o;
    o.x = f2bf(tile[tc + 0][tr]);
    o.y = f2bf(tile[tc + 1][tr]);
    o.z = f2bf(tile[tc + 2][tr]);
    o.w = f2bf(tile[tc + 3][tr]);
    *(ushort4*)(WT + (size_t)(n0 + tr) * K + k0 + tc) = o;
}

// ---------- row L2-normalize, bf16 in-place, width 512 ----------------------
__global__ __launch_bounds__(128) void normalize_bf16_kernel(
    unsigned short* __restrict__ X)
{
    const int r = blockIdx.x;
    const int t = threadIdx.x;
    unsigned short* row = X + (size_t)r * 512;
    ushort4 u = *(const ushort4*)(row + t * 4);
    float x0 = bf2f(u.x), x1 = bf2f(u.y), x2 = bf2f(u.z), x3 = bf2f(u.w);
    float ss = x0 * x0 + x1 * x1 + x2 * x2 + x3 * x3;
#pragma unroll
    for (int off = 32; off > 0; off >>= 1) ss += __shfl_down(ss, off, 64);
    __shared__ float sred[2];
    if ((t & 63) == 0) sred[t >> 6] = ss;
    __syncthreads();
    float inv = 1.0f / sqrtf(sred[0] + sred[1]);
    ushort4 o;
    o.x = f2bf(x0 * inv); o.y = f2bf(x1 * inv);
    o.z = f2bf(x2 * inv); o.w = f2bf(x3 * inv);
    *(ushort4*)(row + t * 4) = o;
}

// ---------- per-row mining + loss (v6: 256 thr, raw-reg retention) ----------
__global__ __launch_bounds__(256, 4) void row_loss_kernel(
    const unsigned short* __restrict__ S, int row_base,
    const float* __restrict__ mw, int midx, float* __restrict__ accum)
{
    __shared__ unsigned hist[4096];         // 16 KB
    __shared__ unsigned wtot[4];
    __shared__ float fred[4];
    __shared__ unsigned sh_b;
    __shared__ float sh_diag;

    const int t    = threadIdx.x;           // 0..255
    const int lane = t & 63;
    const int wv   = t >> 6;                // 0..3
    const int i    = row_base + blockIdx.x; // diag column index
    const unsigned short* Srow = S + (size_t)blockIdx.x * 8192;

    for (int b = t; b < 4096; b += 256) hist[b] = 0;

    uint4 raw[4];
#pragma unroll
    for (int seg = 0; seg < 4; ++seg)
        raw[seg] = *(const uint4*)(Srow + seg * 2048 + t * 8);
    __syncthreads();     // hist zeroed

#pragma unroll
    for (int seg = 0; seg < 4; ++seg) {
        const unsigned short* e = (const unsigned short*)&raw[seg];
#pragma unroll
        for (int q = 0; q < 8; ++q) {
            const int j = seg * 2048 + t * 8 + q;
            const float s = bf2f(e[q]);
            if (j != i && s <= 9.0f) {
                int k = (int)((s + 10.25f) * 200.0f);
                k = k < 1 ? 1 : (k > 4095 ? 4095 : k);
                atomicAdd(&hist[k], 1u);
            }
        }
    }
    __syncthreads();

    unsigned local = 0;
#pragma unroll
    for (int q = 0; q < 16; ++q) local += hist[t * 16 + q];
    unsigned suf = local;
#pragma unroll
    for (int off = 1; off < 64; off <<= 1) {
        unsigned v = __shfl_down(suf, off, 64);
        if (lane + off < 64) suf += v;
    }
    if (lane == 0) wtot[wv] = suf;
    __syncthreads();
    unsigned wsuf = 0;
#pragma unroll
    for (int q = 0; q < 4; ++q) wsuf += (q > wv) ? wtot[q] : 0u;
    suf += wsuf;

    const unsigned target = 4096;
    const unsigned above  = suf - local;
    if (suf >= target && above < target) {
        unsigned cum = above;
        int bsel = t * 16;
#pragma unroll
        for (int q = 15; q >= 0; --q) {
            unsigned c = hist[t * 16 + q];
            if (cum + c >= target) { bsel = t * 16 + q; break; }
            cum += c;
        }
        sh_b = (unsigned)bsel;
    }
    if (t == 0 && suf < target) sh_b = 1u;
    __syncthreads();
    const unsigned bsel = sh_b;

    float lsum = 0.0f;
#pragma unroll
    for (int seg = 0; seg < 4; ++seg) {
        const unsigned short* e = (const unsigned short*)&raw[seg];
#pragma unroll
        for (int q = 0; q < 8; ++q) {
            const int j = seg * 2048 + t * 8 + q;
            const float s = bf2f(e[q]);
            bool diag  = (j == i);
            bool noise = (!diag && s > 9.0f);
            int k = (int)((s + 10.25f) * 200.0f);
            k = k < 1 ? 1 : (k > 4095 ? 4095 : k);
            bool hard = !diag && !noise && ((unsigned)k >= bsel);
            float wgt = noise ? 0.5f : (hard ? 1.5f : 1.0f);
            float ws = s * wgt;
            if (diag) sh_diag = ws;
            lsum += __expf(ws - 16.0f);
        }
    }
#pragma unroll
    for (int off = 32; off > 0; off >>= 1)
        lsum += __shfl_down(lsum, off, 64);
    if (lane == 0) fred[wv] = lsum;
    __syncthreads();
    if (t == 0) {
        float total = fred[0] + fred[1] + fred[2] + fred[3];
        float lse = 16.0f + logf(total);
        float ce = lse - sh_diag;
        atomicAdd(&accum[midx * 64 + (blockIdx.x & 63)],
                  ce * mw[(size_t)i * 2 + midx]);
    }
}

__global__ void zero_kernel(float* __restrict__ accum)
{
    if (threadIdx.x < 128) accum[threadIdx.x] = 0.0f;
}

__global__ void finalize_kernel(const float* __restrict__ accum,
                                float* __restrict__ out)
{
    float s = 0.0f;
    for (int q = 0; q < 128; ++q) s += accum[q];
    out[0] = s * (1.0f / 16384.0f);
}

// ---------------------------------------------------------------------------
extern "C" void kernel_launch(void* const* d_in, const int* in_sizes, int n_in,
                              void* d_out, int out_size, void* d_ws, size_t ws_size,
                              hipStream_t stream)
{
    (void)in_sizes; (void)n_in; (void)out_size; (void)ws_size;

    const float* id_emb = (const float*)d_in[0];
    const float* feats[2] = { (const float*)d_in[1], (const float*)d_in[2] };
    const float* mw     = (const float*)d_in[3];
    const float* Wa[2]  = { (const float*)d_in[4],  (const float*)d_in[6]  };
    const float* ba[2]  = { (const float*)d_in[5],  (const float*)d_in[7]  };
    const float* W1[2]  = { (const float*)d_in[8],  (const float*)d_in[12] };
    const float* b1[2]  = { (const float*)d_in[9],  (const float*)d_in[13] };
    const float* W2[2]  = { (const float*)d_in[10], (const float*)d_in[14] };
    const float* b2[2]  = { (const float*)d_in[11], (const float*)d_in[15] };
    const int    Fdim[2] = { 768, 2048 };

    char* p = (char*)d_ws;
    unsigned short* WaT   = (unsigned short*)p; p += (size_t)1024 * 2048 * 2;  //  4 MB
    unsigned short* W1T   = (unsigned short*)p; p += (size_t)1024 * 1024 * 2;  //  2 MB
    unsigned short* W2T   = (unsigned short*)p; p += (size_t)512  * 1024 * 2;  //  1 MB
    unsigned short* X     = (unsigned short*)p; p += (size_t)16384 * 1024 * 2; // 32 MB
    unsigned short* featb = (unsigned short*)p; p += (size_t)8192 * 2048 * 2;  // 32 MB
    unsigned short* H     = (unsigned short*)p; p += (size_t)16384 * 1024 * 2; // 32 MB
    unsigned short* PB    = (unsigned short*)p; p += (size_t)16384 * 512  * 2; // 16 MB
    float*          accum = (float*)p;          // 128 floats (2 x 64 slots)
    unsigned short* S     = featb;               // 4096x8192 bf16 = 64 MB

    zero_kernel<<<1, 128, 0, stream>>>(accum);

    cast_bf16_kernel<<<(8192 * 1024 / 4 + 255) / 256, 256, 0, stream>>>(
        id_emb, X + (size_t)8192 * 1024, 8192 * 1024 / 4);

    for (int m = 0; m < 2; ++m) {
        const int F = Fdim[m];

        cast_bf16_kernel<<<(8192 * F / 4 + 255) / 256, 256, 0, stream>>>(
            feats[m], featb, 8192 * F / 4);
        transpose_cast_kernel<<<dim3(1024 / 32, F / 32), 256, 0, stream>>>(
            Wa[m], WaT, F, 1024);
        transpose_cast_kernel<<<dim3(1024 / 32, 1024 / 32), 256, 0, stream>>>(
            W1[m], W1T, 1024, 1024);
        transpose_cast_kernel<<<dim3(512 / 32, 1024 / 32), 256, 0, stream>>>(
            W2[m], W2T, 1024, 512);

        // X[0:8192] = feat @ Wa + ba   (8192 x 1024)  -- 128x128 kernel
        gemm_bt_mfma<<<(8192 / 128) * (1024 / 128), 256, 0, stream>>>(
            featb, F, WaT, F, X, 1024, 8192, 1024, F, ba[m], 0, 1.0f);

        // H = relu(X @ W1 + b1)        (16384 x 1024) -- 256x256 kernel
        gemm_bt_256<<<(16384 / 256) * (1024 / 256), 512, 0, stream>>>(
            X, 1024, W1T, 1024, H, 1024, 16384, 1024, 1024, b1[m], 1, 1.0f);
        // PB = H @ W2 + b2             (16384 x 512)  -- 128x128 kernel
        gemm_bt_mfma<<<(16384 / 128) * (512 / 128), 256, 0, stream>>>(
            H, 1024, W2T, 1024, PB, 512, 16384, 512, 1024, b2[m], 0, 1.0f);
        normalize_bf16_kernel<<<16384, 128, 0, stream>>>(PB);

        const unsigned short* mproj = PB;
        const unsigned short* iproj = PB + (size_t)8192 * 512;

        for (int c = 0; c < 2; ++c) {
            // S = 10 * id_proj[chunk] @ modal_proj^T (4096 x 8192) -- 256x256
            gemm_bt_256<<<(4096 / 256) * (8192 / 256), 512, 0, stream>>>(
                iproj + (size_t)c * 4096 * 512, 512, mproj, 512,
                S, 8192, 4096, 8192, 512, nullptr, 0, 10.0f);
            row_loss_kernel<<<4096, 256, 0, stream>>>(
                S, c * 4096, mw, m, accum);
        }
    }

    finalize_kernel<<<1, 1, 0, stream>>>(accum, (float*)d_out);
}